// Round 18
// baseline (1857.743 us; speedup 1.0000x reference)
//
#include <hip/hip_runtime.h>

#define T_ 2048
#define H_ 1024
#define S_ 1024
#define V_ 32000
#define I_ 2048
#define NHD 1024   // NH*HD
#define KVD 512    // NKV*HD

typedef unsigned short u16;
typedef unsigned int u32;
typedef __attribute__((ext_vector_type(8))) short s16x8;
typedef __attribute__((ext_vector_type(4))) float f32x4;

__device__ __forceinline__ u16 f2b(float f){ u32 x=__builtin_bit_cast(u32,f); return (u16)((x+0x7fffu+((x>>16)&1u))>>16); }
__device__ __forceinline__ float b2f(u16 u){ return __builtin_bit_cast(float,(u32)u<<16); }
__device__ __forceinline__ float wsum(float v){ for(int o=32;o;o>>=1) v+=__shfl_xor(v,o); return v; }

// async global->LDS, 16B per lane; LDS dest = wave-uniform base + lane*16
__device__ __forceinline__ void gl16(const void* g, void* l){
  __builtin_amdgcn_global_load_lds(
      (const __attribute__((address_space(1))) unsigned int*)g,
      (__attribute__((address_space(3))) unsigned int*)l, 16, 0, 0);
}

// ---------------- embedding gather (+ expert counter zero) ----------------
__global__ void k_embed(const int* __restrict__ ids, const float* __restrict__ emb,
                        float* __restrict__ h, int* __restrict__ cnt){
  if(blockIdx.x==0 && threadIdx.x<16) cnt[threadIdx.x]=0;
  int t = blockIdx.x;
  long src = (long)ids[t]*H_;
  ((float4*)(h + (long)t*H_))[threadIdx.x] = ((const float4*)(emb+src))[threadIdx.x];
}

// ---------------- rmsnorm: fp32 -> bf16 hi(/lo) planes ----------------
__global__ void k_rms_sp(const float* __restrict__ h, const float* __restrict__ w,
                         u16* __restrict__ xhi, u16* __restrict__ xlo){
  int wid = threadIdx.x>>6, lane = threadIdx.x&63;
  int t = blockIdx.x*4 + wid;
  const float* row = h + (long)t*H_;
  float v[16]; float ss=0.f;
  #pragma unroll
  for(int j=0;j<16;j++){ v[j]=row[j*64+lane]; ss += v[j]*v[j]; }
  ss = wsum(ss);
  float rstd = rsqrtf(ss/(float)H_ + 1e-6f);
  #pragma unroll
  for(int j=0;j<16;j++){
    int idx=j*64+lane;
    float y = v[j]*rstd*w[idx];
    u16 hv = f2b(y);
    xhi[(long)t*H_+idx] = hv;
    if(xlo) xlo[(long)t*H_+idx] = f2b(y - b2f(hv));
  }
}

// ---------------- router (fp32) + expert list build + ln2 planes (merged) ----------------
__global__ void k_router(const float* __restrict__ h, const float* __restrict__ lw,
                         const float* __restrict__ gate, float* __restrict__ comb,
                         int* __restrict__ lists, int* __restrict__ cnt, int2* __restrict__ epos,
                         u16* __restrict__ xhi, u16* __restrict__ xlo){
  int wid = threadIdx.x>>6, lane = threadIdx.x&63;
  int t = blockIdx.x*4+wid;
  const float* row = h + (long)t*H_;
  float v[16]; float ss=0.f;
  #pragma unroll
  for(int j=0;j<16;j++){ v[j]=row[j*64+lane]; ss+=v[j]*v[j]; }
  ss = wsum(ss);
  float rstd = rsqrtf(ss/(float)H_+1e-6f);
  float a0=0,a1=0,a2=0,a3=0;
  #pragma unroll
  for(int j=0;j<16;j++){
    int idx=j*64+lane;
    float y = v[j]*rstd*lw[idx];
    u16 hv = f2b(y);
    xhi[(long)t*H_+idx] = hv;
    xlo[(long)t*H_+idx] = f2b(y - b2f(hv));
    float4 g4 = ((const float4*)gate)[idx];
    a0 += y*g4.x; a1 += y*g4.y; a2 += y*g4.z; a3 += y*g4.w;
  }
  a0=wsum(a0); a1=wsum(a1); a2=wsum(a2); a3=wsum(a3);
  if(lane==0){
    float p[4]={a0,a1,a2,a3};
    float m = fmaxf(fmaxf(p[0],p[1]),fmaxf(p[2],p[3]));
    float s=0; for(int e=0;e<4;e++){ p[e]=__expf(p[e]-m); s+=p[e]; }
    for(int e=0;e<4;e++) p[e]/=s;
    int i1=0; for(int e=1;e<4;e++) if(p[e]>p[i1]) i1=e;
    int i2=-1; for(int e=0;e<4;e++){ if(e==i1) continue; if(i2<0||p[e]>p[i2]) i2=e; }
    float* c = comb + (long)t*4;
    for(int e=0;e<4;e++) c[e] = (e==i1||e==i2)? p[e] : 0.f;
    int p1 = atomicAdd(&cnt[i1],1); lists[i1*T_+p1]=t;
    int p2 = atomicAdd(&cnt[i2],1); lists[i2*T_+p2]=t;
    epos[t] = make_int2((p1<<2)|i1, (p2<<2)|i2);
  }
}

// ---------------- transpose+split: fp32 [R][C] -> bf16 hi(+lo) [C][R] ----------------
__global__ void k_transpose(const float* __restrict__ in, u16* __restrict__ hi, u16* __restrict__ lo,
                            int R, int C, long zi, long zo){
  __shared__ float tile[32][33];
  in += (long)blockIdx.z*zi; hi += (long)blockIdx.z*zo; if(lo) lo += (long)blockIdx.z*zo;
  int c0 = blockIdx.x*32, r0 = blockIdx.y*32;
  int tx = threadIdx.x, ty = threadIdx.y;
  #pragma unroll
  for(int i=0;i<4;i++) tile[ty+8*i][tx] = in[(long)(r0+ty+8*i)*C + c0+tx];
  __syncthreads();
  #pragma unroll
  for(int i=0;i<4;i++){
    int cc=ty+8*i; float v = tile[tx][cc];
    u16 hv = f2b(v);
    long idx = (long)(c0+cc)*R + r0+tx;
    hi[idx] = hv;
    if(lo) lo[idx] = f2b(v - b2f(hv));
  }
}

// ---------------- all per-layer weight transposes in ONE launch ----------------
__global__ void k_wtrans(const float* __restrict__ Wq, const float* __restrict__ Wk,
                         const float* __restrict__ Wv, const float* __restrict__ Wo,
                         const float* __restrict__ Wg, const float* __restrict__ Wu,
                         const float* __restrict__ Wd,
                         u16* __restrict__ qkvh, u16* __restrict__ qkvl,
                         u16* __restrict__ oh, u16* __restrict__ ol,
                         u16* __restrict__ gh, u16* __restrict__ gl_,
                         u16* __restrict__ uh, u16* __restrict__ ul,
                         u16* __restrict__ dh, u16* __restrict__ dl)
{
  __shared__ float tile[32][33];
  int id = blockIdx.x;
  const float* in; u16 *hi, *lo; int R, C, bx, by;
  if(id < 1024){ in=Wq; hi=qkvh; lo=qkvl; R=1024; C=1024; bx=id&31; by=id>>5; }
  else if(id < 1536){ id-=1024; in=Wk; hi=qkvh+1048576; lo=qkvl+1048576; R=1024; C=512; bx=id&15; by=id>>4; }
  else if(id < 2048){ id-=1536; in=Wv; hi=qkvh+1572864; lo=qkvl+1572864; R=1024; C=512; bx=id&15; by=id>>4; }
  else if(id < 3072){ id-=2048; in=Wo; hi=oh; lo=ol; R=1024; C=1024; bx=id&31; by=id>>5; }
  else if(id < 11264){ id-=3072; int z=id>>11, r2=id&2047;
    in=Wg+(size_t)z*H_*I_; hi=gh+(size_t)z*I_*H_; lo=gl_+(size_t)z*I_*H_;
    R=1024; C=2048; bx=r2&63; by=r2>>6; }
  else if(id < 19456){ id-=11264; int z=id>>11, r2=id&2047;
    in=Wu+(size_t)z*H_*I_; hi=uh+(size_t)z*I_*H_; lo=ul+(size_t)z*I_*H_;
    R=1024; C=2048; bx=r2&63; by=r2>>6; }
  else { id-=19456; int z=id>>11, r2=id&2047;
    in=Wd+(size_t)z*I_*H_; hi=dh+(size_t)z*H_*I_; lo=dl+(size_t)z*H_*I_;
    R=2048; C=1024; bx=r2&31; by=r2>>5; }
  int c0=bx*32, r0=by*32, tx=threadIdx.x, ty=threadIdx.y;
  #pragma unroll
  for(int i=0;i<4;i++) tile[ty+8*i][tx] = in[(long)(r0+ty+8*i)*C + c0+tx];
  __syncthreads();
  #pragma unroll
  for(int i=0;i<4;i++){
    int cc=ty+8*i; float v = tile[tx][cc];
    u16 hv = f2b(v);
    long idx = (long)(c0+cc)*R + r0+tx;
    hi[idx] = hv;
    lo[idx] = f2b(v - b2f(hv));
  }
}

// ---------------- MoE combine + fused next-layer rmsnorm planes ----------------
__global__ void k_combine(float* __restrict__ h, const float* __restrict__ eo,
                          const int2* __restrict__ epos, const float* __restrict__ comb,
                          const float* __restrict__ wn, u16* __restrict__ xhi, u16* __restrict__ xlo){
  int t = blockIdx.x, c = threadIdx.x;
  int lane = c&63, wid = c>>6;
  int2 ep = epos[t];
  int e1 = ep.x&3, p1 = ep.x>>2, e2 = ep.y&3, p2 = ep.y>>2;
  float c1 = comb[t*4+e1], c2 = comb[t*4+e2];
  float4 a = ((const float4*)(eo + (long)(e1*T_+p1)*H_))[c];
  float4 b = ((const float4*)(eo + (long)(e2*T_+p2)*H_))[c];
  float4* hp = (float4*)(h + (long)t*H_) + c;
  float4 hv = *hp;
  hv.x += c1*a.x + c2*b.x; hv.y += c1*a.y + c2*b.y;
  hv.z += c1*a.z + c2*b.z; hv.w += c1*a.w + c2*b.w;
  *hp = hv;
  __shared__ float red[4];
  float ss = hv.x*hv.x + hv.y*hv.y + hv.z*hv.z + hv.w*hv.w;
  ss = wsum(ss);
  if(lane==0) red[wid]=ss;
  __syncthreads();
  float tot = red[0]+red[1]+red[2]+red[3];
  float rstd = rsqrtf(tot*(1.f/1024.f) + 1e-6f);
  float4 wv = ((const float4*)wn)[c];
  float y0=hv.x*rstd*wv.x, y1=hv.y*rstd*wv.y, y2=hv.z*rstd*wv.z, y3=hv.w*rstd*wv.w;
  ushort4 Hv; Hv.x=f2b(y0); Hv.y=f2b(y1); Hv.z=f2b(y2); Hv.w=f2b(y3);
  ((ushort4*)(xhi + (long)t*H_))[c] = Hv;
  if(xlo){
    ushort4 Lv;
    Lv.x=f2b(y0-b2f(Hv.x)); Lv.y=f2b(y1-b2f(Hv.y));
    Lv.z=f2b(y2-b2f(Hv.z)); Lv.w=f2b(y3-b2f(Hv.w));
    ((ushort4*)(xlo + (long)t*H_))[c] = Lv;
  }
}

// ---------------- fused flash attention (QBLK=128, 8 waves, co-staged K/V, 2 barriers/tile) ----------------
__global__ __launch_bounds__(512) void k_flash(
  const u16* __restrict__ qh_g, const u16* __restrict__ ql_g,
  const u16* __restrict__ kh_g, const u16* __restrict__ kl_g,
  const u16* __restrict__ vth_g, const u16* __restrict__ vtl_g,
  u16* __restrict__ oh_g, u16* __restrict__ ol_g)
{
  __shared__ alignas(16) u16 Kh[8192], Kl[8192];
  __shared__ alignas(16) u16 Vh[8192], Vl[8192];
  __shared__ alignas(16) u16 Ph[16384], Pl[16384];
  const int qt = blockIdx.x, hh = blockIdx.y, b = blockIdx.z;
  const int hk = hh>>1;
  const int lane = threadIdx.x&63, w = threadIdx.x>>6;
  const int rA = lane&15, kg = (lane>>4)*8;

  s16x8 qfh[2], qfl[2];
  {
    long t = (long)(b*1024+qt*128) + w*16 + rA;
    const u16* qp = qh_g + t*NHD + hh*64;
    const u16* qp2= ql_g + t*NHD + hh*64;
    qfh[0]=*(const s16x8*)(qp + kg);      qfh[1]=*(const s16x8*)(qp + 32 + kg);
    qfl[0]=*(const s16x8*)(qp2 + kg);     qfl[1]=*(const s16x8*)(qp2 + 32 + kg);
  }

  const int ktend = qt+1;
  {
    const u16* kp = kh_g + ((long)(b*1024))*KVD + hk*64;
    const u16* kp2= kl_g + ((long)(b*1024))*KVD + hk*64;
    #pragma unroll
    for(int s=0;s<2;s++){
      int idx=s*8+w, hf=idx>>3, g=idx&7;
      int row = g*16 + (lane>>2);
      int c8  = hf*32 + (lane&3)*8;
      gl16(kp  + (long)row*KVD + c8, &Kh[hf*4096 + g*512]);
      gl16(kp2 + (long)row*KVD + c8, &Kl[hf*4096 + g*512]);
    }
  }

  f32x4 Oa[4];
  float mrun[4], lrun[4];
  #pragma unroll
  for(int jn=0;jn<4;jn++){ f32x4 zv={0.f,0.f,0.f,0.f}; Oa[jn]=zv; }
  #pragma unroll
  for(int r=0;r<4;r++){ mrun[r]=-3.0e38f; lrun[r]=0.f; }

  __syncthreads();

  for(int kt=0; kt<ktend; kt++){
    {
      const u16* vp = vth_g + (long)b*((long)KVD*S_) + (long)(hk*64)*S_ + kt*128;
      const u16* vp2= vtl_g + (long)b*((long)KVD*S_) + (long)(hk*64)*S_ + kt*128;
      #pragma unroll
      for(int s=0;s<2;s++){
        int idx=s*8+w, ks=idx>>2, g=idx&3;
        int dr = g*16 + (lane>>2);
        int k8 = (lane&3)*8;
        gl16(vp  + (long)dr*S_ + ks*32 + k8, &Vh[ks*2048 + g*512]);
        gl16(vp2 + (long)dr*S_ + ks*32 + k8, &Vl[ks*2048 + g*512]);
      }
    }

    f32x4 Sf[8];
    #pragma unroll
    for(int j=0;j<8;j++){ f32x4 zv={0.f,0.f,0.f,0.f}; Sf[j]=zv; }
    #pragma unroll
    for(int k2=0;k2<2;k2++){
      s16x8 bh[8],bl[8];
      #pragma unroll
      for(int j=0;j<8;j++){
        int ky = j*16+rA;
        bh[j]=*(const s16x8*)&Kh[k2*4096 + ky*32 + kg];
        bl[j]=*(const s16x8*)&Kl[k2*4096 + ky*32 + kg];
      }
      #pragma unroll
      for(int j=0;j<8;j++){
        Sf[j]=__builtin_amdgcn_mfma_f32_16x16x32_bf16(qfh[k2],bh[j],Sf[j],0,0,0);
        Sf[j]=__builtin_amdgcn_mfma_f32_16x16x32_bf16(qfh[k2],bl[j],Sf[j],0,0,0);
        Sf[j]=__builtin_amdgcn_mfma_f32_16x16x32_bf16(qfl[k2],bh[j],Sf[j],0,0,0);
      }
    }

    const bool last = (kt==ktend-1);
    #pragma unroll
    for(int j=0;j<8;j++)
      #pragma unroll
      for(int r=0;r<4;r++){
        float sv = Sf[j][r]*0.125f;
        if(last){
          int qr = qt*128 + w*16 + ((lane>>4)<<2) + r;
          int ky = kt*128 + j*16 + (lane&15);
          if(ky>qr) sv = -3.0e38f;
        }
        Sf[j][r]=sv;
      }

    float mt[4];
    #pragma unroll
    for(int r=0;r<4;r++){
      float v = Sf[0][r];
      #pragma unroll
      for(int j=1;j<8;j++) v = fmaxf(v, Sf[j][r]);
      v=fmaxf(v,__shfl_xor(v,1)); v=fmaxf(v,__shfl_xor(v,2));
      v=fmaxf(v,__shfl_xor(v,4)); v=fmaxf(v,__shfl_xor(v,8));
      mt[r]=v;
    }

    #pragma unroll
    for(int r=0;r<4;r++){
      float mo=mrun[r];
      float mn=fmaxf(mo,mt[r]);
      float al_=__expf(mo-mn);
      mrun[r]=mn;
      lrun[r]*=al_;
      #pragma unroll
      for(int jn=0;jn<4;jn++) Oa[jn][r]*=al_;
    }

    float ls[4];
    #pragma unroll
    for(int r=0;r<4;r++) ls[r]=0.f;
    #pragma unroll
    for(int j=0;j<8;j++)
      #pragma unroll
      for(int r=0;r<4;r++){
        int q  = w*16+((lane>>4)<<2)+r;
        int ky = j*16+(lane&15);
        float pv=__expf(Sf[j][r]-mrun[r]);
        ls[r]+=pv;
        u16 hv=f2b(pv);
        int a=(ky>>5)*4096 + q*32 + (ky&31);
        Ph[a]=hv; Pl[a]=f2b(pv-b2f(hv));
      }
    #pragma unroll
    for(int r=0;r<4;r++){
      float v=ls[r];
      v+=__shfl_xor(v,1); v+=__shfl_xor(v,2); v+=__shfl_xor(v,4); v+=__shfl_xor(v,8);
      lrun[r]+=v;
    }
    __syncthreads();

    if(kt+1<ktend){
      const u16* kp = kh_g + ((long)(b*1024+(kt+1)*128))*KVD + hk*64;
      const u16* kp2= kl_g + ((long)(b*1024+(kt+1)*128))*KVD + hk*64;
      #pragma unroll
      for(int s=0;s<2;s++){
        int idx=s*8+w, hf=idx>>3, g=idx&7;
        int row = g*16 + (lane>>2);
        int c8  = hf*32 + (lane&3)*8;
        gl16(kp  + (long)row*KVD + c8, &Kh[hf*4096 + g*512]);
        gl16(kp2 + (long)row*KVD + c8, &Kl[hf*4096 + g*512]);
      }
    }

    #pragma unroll
    for(int ks=0;ks<4;ks++){
      s16x8 pah,pal,vbh[4],vbl[4];
      int q = w*16+rA;
      pah=*(const s16x8*)&Ph[ks*4096 + q*32 + kg];
      pal=*(const s16x8*)&Pl[ks*4096 + q*32 + kg];
      #pragma unroll
      for(int jn=0;jn<4;jn++){
        int d = jn*16+rA;
        vbh[jn]=*(const s16x8*)&Vh[ks*2048 + d*32 + kg];
        vbl[jn]=*(const s16x8*)&Vl[ks*2048 + d*32 + kg];
      }
      #pragma unroll
      for(int jn=0;jn<4;jn++){
        Oa[jn]=__builtin_amdgcn_mfma_f32_16x16x32_bf16(pah,vbh[jn],Oa[jn],0,0,0);
        Oa[jn]=__builtin_amdgcn_mfma_f32_16x16x32_bf16(pah,vbl[jn],Oa[jn],0,0,0);
        Oa[jn]=__builtin_amdgcn_mfma_f32_16x16x32_bf16(pal,vbh[jn],Oa[jn],0,0,0);
      }
    }
    __syncthreads();
  }

  #pragma unroll
  for(int jn=0;jn<4;jn++)
    #pragma unroll
    for(int r=0;r<4;r++){
      long t = (long)b*1024 + qt*128 + w*16+((lane>>4)<<2)+r;
      int col = hh*64 + jn*16 + (lane&15);
      float ov = Oa[jn][r] / lrun[r];
      u16 hv=f2b(ov);
      oh_g[t*NHD+col]=hv;
      ol_g[t*NHD+col]=f2b(ov-b2f(hv));
    }
}

// ---------------- fused QKV GEMM (gload staging, BK=64, swizzled LDS) ----------------
__global__ __launch_bounds__(256) void k_qkv(
  const u16* __restrict__ xhi, const u16* __restrict__ xlo,
  const u16* __restrict__ Bh, const u16* __restrict__ Bl,
  u16* __restrict__ qhi, u16* __restrict__ qlo,
  u16* __restrict__ khi, u16* __restrict__ klo,
  u16* __restrict__ vthi, u16* __restrict__ vtlo)
{
  __shared__ alignas(16) u16 As[2*128*64], Bs[2*128*64];
  const int m0=blockIdx.x*128, n0=blockIdx.y*128;
  const int tid=threadIdx.x, lane=tid&63, w=tid>>6, wr=w>>1, wc=w&1;
  const int rsub = lane>>3;
  const int col8 = ((lane&7) ^ (rsub&7))*8;
  const int kq = lane>>4;
  f32x4 acc[4][4];
  #pragma unroll
  for(int i=0;i<4;i++)
    #pragma unroll
    for(int j=0;j<4;j++){ f32x4 zv={0.f,0.f,0.f,0.f}; acc[i][j]=zv; }

  for(int kt=0;kt<16;kt++){
    const int k0=kt*64;
    __syncthreads();
    #pragma unroll
    for(int s=0;s<4;s++){
      int ch=s*4+w; int row=ch*8+rsub;
      gl16(xhi + (long)(m0+row)*H_ + k0+col8, &As[ch*512]);
      gl16(xlo + (long)(m0+row)*H_ + k0+col8, &As[8192+ch*512]);
      gl16(Bh  + (long)(n0+row)*H_ + k0+col8, &Bs[ch*512]);
      gl16(Bl  + (long)(n0+row)*H_ + k0+col8, &Bs[8192+ch*512]);
    }
    __syncthreads();
    #pragma unroll
    for(int ks=0;ks<2;ks++){
      s16x8 ah[4],al[4],bh[4],bl[4];
      #pragma unroll
      for(int i=0;i<4;i++){
        int row = wr*64+i*16+(lane&15);
        int sl = ((ks*4+kq) ^ (row&7))*8;
        ah[i]=*(const s16x8*)&As[row*64+sl];
        al[i]=*(const s16x8*)&As[8192+row*64+sl];
      }
      #pragma unroll
      for(int j=0;j<4;j++){
        int row = wc*64+j*16+(lane&15);
        int sl = ((ks*4+kq) ^ (row&7))*8;
        bh[j]=*(const s16x8*)&Bs[row*64+sl];
        bl[j]=*(const s16x8*)&Bs[8192+row*64+sl];
      }
      #pragma unroll
      for(int i=0;i<4;i++)
        #pragma unroll
        for(int j=0;j<4;j++){
          acc[i][j]=__builtin_amdgcn_mfma_f32_16x16x32_bf16(ah[i],bh[j],acc[i][j],0,0,0);
          acc[i][j]=__builtin_amdgcn_mfma_f32_16x16x32_bf16(ah[i],bl[j],acc[i][j],0,0,0);
          acc[i][j]=__builtin_amdgcn_mfma_f32_16x16x32_bf16(al[i],bh[j],acc[i][j],0,0,0);
        }
    }
  }

  #pragma unroll
  for(int i=0;i<4;i++){
    #pragma unroll
    for(int j=0;j<4;j++){
      const int gm0 = m0 + wr*64 + i*16 + ((lane>>4)<<2);
      const int gn  = n0 + wc*64 + j*16 + (lane&15);
      #pragma unroll
      for(int r=0;r<4;r++){
        const int gm = gm0+r;
        float v = acc[i][j][r];
        u16 hv = f2b(v);
        u16 lv = f2b(v - b2f(hv));
        if(gn < 1024){
          long idx=(long)gm*NHD+gn; qhi[idx]=hv; qlo[idx]=lv;
        } else if(gn < 1536){
          long idx=(long)gm*KVD+(gn-1024); khi[idx]=hv; klo[idx]=lv;
        } else {
          long idx=((long)(gm>>10)<<19) + (long)(gn-1536)*S_ + (gm&1023);
          vthi[idx]=hv; vtlo[idx]=lv;
        }
      }
    }
  }
}

// ---------------- fused MoE up+gate (gload, BK=64, swizzled, XCD-grouped 1D grid) ----------------
__global__ __launch_bounds__(256) void k_moe_ug(
  const u16* __restrict__ xhi, const u16* __restrict__ xlo,
  const u16* __restrict__ Wuh, const u16* __restrict__ Wul,
  const u16* __restrict__ Wgh, const u16* __restrict__ Wgl,
  u16* __restrict__ guh, u16* __restrict__ gul,
  const int* __restrict__ lists, const int* __restrict__ cntp)
{
  const int bb = blockIdx.x;
  const int xcd = bb&7, bidx = bb>>3;
  const int grp = xcd + 8*(bidx>>4);
  const int mslot = bidx&15;
  const int e = grp>>5;
  const int n0 = (grp&31)*64;
  const int m0 = mslot*128;
  const int ce = cntp[e];
  if(m0>=ce) return;
  const int* ridx = lists + e*T_;
  const u16* Buh_g = Wuh + (size_t)e*H_*I_;
  const u16* Bul_g = Wul + (size_t)e*H_*I_;
  const u16* Bgh_g = Wgh + (size_t)e*H_*I_;
  const u16* Bgl_g = Wgl + (size_t)e*H_*I_;
  __shared__ alignas(16) u16 Ah[128*64], Al[128*64];
  __shared__ alignas(16) u16 Buh[64*64], Bul[64*64], Bgh[64*64], Bgl[64*64];
  const int tid=threadIdx.x, lane=tid&63, w=tid>>6;
  const int wr=w>>1, wc=w&1;
  const int rsub = lane>>3;
  const int col8 = ((lane&7) ^ (rsub&7))*8;
  const int kq = lane>>4;
  int arA[4];
  #pragma unroll
  for(int s=0;s<4;s++){ int idx=m0 + (s*4+w)*8 + rsub; arA[s]=ridx[idx<ce?idx:ce-1]; }
  f32x4 au[4][2], ag[4][2];
  #pragma unroll
  for(int i=0;i<4;i++)
    #pragma unroll
    for(int j=0;j<2;j++){ f32x4 zv={0.f,0.f,0.f,0.f}; au[i][j]=zv; ag[i][j]=zv; }

  for(int kt=0;kt<16;kt++){
    const int k0=kt*64;
    __syncthreads();
    #pragma unroll
    for(int s=0;s<4;s++){
      int ch=s*4+w;
      gl16(xhi + (long)arA[s]*H_ + k0+col8, &Ah[ch*512]);
      gl16(xlo + (long)arA[s]*H_ + k0+col8, &Al[ch*512]);
    }
    #pragma unroll
    for(int s=0;s<2;s++){
      int ch=s*4+w;
      int brow = n0 + ch*8 + rsub;
      gl16(Buh_g + (long)brow*H_ + k0+col8, &Buh[ch*512]);
      gl16(Bul_g + (long)brow*H_ + k0+col8, &Bul[ch*512]);
      gl16(Bgh_g + (long)brow*H_ + k0+col8, &Bgh[ch*512]);
      gl16(Bgl_g + (long)brow*H_ + k0+col8, &Bgl[ch*512]);
    }
    __syncthreads();
    #pragma unroll
    for(int ks=0;ks<2;ks++){
      s16x8 fah[4],fal[4],fbuh[2],fbul[2],fbgh[2],fbgl[2];
      #pragma unroll
      for(int i=0;i<4;i++){
        int row = wr*64+i*16+(lane&15);
        int sl = ((ks*4+kq) ^ (row&7))*8;
        fah[i]=*(const s16x8*)&Ah[row*64+sl];
        fal[i]=*(const s16x8*)&Al[row*64+sl];
      }
      #pragma unroll
      for(int j=0;j<2;j++){
        int row = wc*32+j*16+(lane&15);
        int sl = ((ks*4+kq) ^ (row&7))*8;
        fbuh[j]=*(const s16x8*)&Buh[row*64+sl];
        fbul[j]=*(const s16x8*)&Bul[row*64+sl];
        fbgh[j]=*(const s16x8*)&Bgh[row*64+sl];
        fbgl[j]=*(const s16x8*)&Bgl[row*64+sl];
      }
      #pragma unroll
      for(int i=0;i<4;i++)
        #pragma unroll
        for(int j=0;j<2;j++){
          au[i][j]=__builtin_amdgcn_mfma_f32_16x16x32_bf16(fah[i],fbuh[j],au[i][j],0,0,0);
          au[i][j]=__builtin_amdgcn_mfma_f32_16x16x32_bf16(fah[i],fbul[j],au[i][j],0,0,0);
          au[i][j]=__builtin_amdgcn_mfma_f32_16x16x32_bf16(fal[i],fbuh[j],au[i][j],0,0,0);
          ag[i][j]=__builtin_amdgcn_mfma_f32_16x16x32_bf16(fah[i],fbgh[j],ag[i][j],0,0,0);
          ag[i][j]=__builtin_amdgcn_mfma_f32_16x16x32_bf16(fah[i],fbgl[j],ag[i][j],0,0,0);
          ag[i][j]=__builtin_amdgcn_mfma_f32_16x16x32_bf16(fal[i],fbgh[j],ag[i][j],0,0,0);
        }
    }
  }

  #pragma unroll
  for(int i=0;i<4;i++){
    #pragma unroll
    for(int j=0;j<2;j++){
      const int gm0 = m0 + wr*64 + i*16 + ((lane>>4)<<2);
      const int gn  = n0 + wc*32 + j*16 + (lane&15);
      #pragma unroll
      for(int r=0;r<4;r++){
        const int gm = gm0+r;
        if(gm<ce){
          float uu=au[i][j][r], gg=ag[i][j][r];
          float val = (gg/(1.f+__expf(-gg)))*uu;
          long idx = (long)(e*T_+gm)*I_ + gn;
          u16 hv=f2b(val);
          guh[idx]=hv; gul[idx]=f2b(val-b2f(hv));
        }
      }
    }
  }
}

// ---------------- generic MFMA GEMM (gload + two-sided swizzle; smem-union; optional 2-phase pipe) ----------------
// BKT: K-step. SPL: bf16x2 split; EPI: 1=f32*scale, 2=f32 +=, 7=f32 compact expert slot,
//      8=f32 via LDS coalesced (Cs aliases stage bufs), 9=split planes
// GATH: 0=dense, 4=expert-slot XCD-grouped 1D; SWZ: XCD-bijective swizzle; PIPE: 2-phase double-buffer
template<int BM,int BN,int WM,int WN,int BKT,bool SPL,int EPI,int GATH,bool SWZ,bool PIPE>
__launch_bounds__(WM*WN*64)
__global__ void k_gemm(const u16* __restrict__ Ahip, const u16* __restrict__ Alop,
                       const u16* __restrict__ Bhip, const u16* __restrict__ Blop,
                       void* __restrict__ Cp, void* __restrict__ auxp,
                       const int* __restrict__ cntp,
                       int Kdim, int lda, int ldb, int ldc,
                       long zA, long zB, int zBdiv, long zC,
                       float scale)
{
  constexpr int NT = WM*WN*64;
  constexpr int Wv = NT/64;
  constexpr int WMT = BM/WM, WNT = BN/WN;
  constexpr int MF = WMT/16, NF = WNT/16;
  constexpr int LPR = BKT/8;
  constexpr int LR  = 64/LPR;
  constexpr int ACn = (BM/LR)/Wv;
  constexpr int BCn = (BN/LR)/Wv;
  constexpr int KS  = BKT/32;
  constexpr int ABY = (SPL?2:1)*BM*BKT*2;
  constexpr int BBY = (SPL?2:1)*BN*BKT*2;
  constexpr int STEP = ABY+BBY;
  constexpr int SBY = (PIPE?2:1)*STEP;
  constexpr int CBY = (EPI==8) ? WM*16*(BN+4)*4 : 0;
  constexpr int SMB = SBY > CBY ? SBY : CBY;
  static_assert(ACn>=1 && BCn>=1, "chunks");
  __shared__ alignas(16) char smem[SMB];
  float* Csf = (float*)smem;
  constexpr int SL = T_/BM;
  int m0, n0, eid_ = 0, cnt = 0;
  if constexpr (GATH==4){
    constexpr int NTN = H_/BN;
    const int bb = blockIdx.x;
    const int xcd = bb&7, bidx = bb>>3;
    const int grp = xcd + 8*(bidx/SL);
    const int mslot = bidx%SL;
    eid_ = grp/NTN; n0 = (grp%NTN)*BN; m0 = mslot*BM;
    cnt = cntp[eid_]; if(m0>=cnt) return;
  } else if constexpr (SWZ){
    int nx = gridDim.x;
    int l = blockIdx.y*nx + blockIdx.x;
    int q = (nx*gridDim.y)>>3;
    int wid = (l&7)*q + (l>>3);
    m0 = (wid % nx)*BM; n0 = (wid / nx)*BN;
  } else {
    m0 = blockIdx.x*BM; n0 = blockIdx.y*BN;
  }
  const int z = blockIdx.z;
  const int tid = threadIdx.x, lane = tid&63, w = tid>>6;
  const int wr = w/WN, wc = w%WN;
  const int rsub = lane/LPR;
  const int col8 = (((lane%LPR) ^ (rsub&(LPR-1))))*8;
  const int kq = lane>>4;
  const u16* Ahi = Ahip + (long)z*zA + (GATH==4 ? (long)eid_*T_*lda : 0);
  const u16* Alo = SPL ? (Alop + (long)z*zA + (GATH==4 ? (long)eid_*T_*lda : 0)) : (const u16*)nullptr;
  const u16* Bh  = Bhip + (long)(z/zBdiv)*zB + (GATH==4 ? (long)eid_*zB : 0);
  const u16* Bl  = SPL ? (Blop + (long)(z/zBdiv)*zB + (GATH==4 ? (long)eid_*zB : 0)) : (const u16*)nullptr;

  f32x4 acc[MF][NF];
  #pragma unroll
  for(int i=0;i<MF;i++)
    #pragma unroll
    for(int j=0;j<NF;j++){ f32x4 zv={0.f,0.f,0.f,0.f}; acc[i][j]=zv; }

  const int ktend = Kdim/BKT;

  auto stage = [&](int kt, int bo){
    u16* As = (u16*)(smem + bo);
    u16* Bs = (u16*)(smem + bo + ABY);
    const int k0 = kt*BKT;
    #pragma unroll
    for(int s=0;s<ACn;s++){
      int ch = s*Wv + w;
      int arow = m0 + ch*LR + rsub;
      if constexpr (GATH==4){ arow = arow < cnt ? arow : cnt-1; }
      gl16(Ahi + (long)arow*lda + k0+col8, &As[ch*512]);
      if constexpr (SPL) gl16(Alo + (long)arow*lda + k0+col8, &As[BM*BKT + ch*512]);
    }
    #pragma unroll
    for(int s=0;s<BCn;s++){
      int ch = s*Wv + w;
      int brow = n0 + ch*LR + rsub;
      gl16(Bh + (long)brow*ldb + k0+col8, &Bs[ch*512]);
      if constexpr (SPL) gl16(Bl + (long)brow*ldb + k0+col8, &Bs[BN*BKT + ch*512]);
    }
  };

  auto compute = [&](int bo){
    u16* As = (u16*)(smem + bo);
    u16* Bs = (u16*)(smem + bo + ABY);
    #pragma unroll
    for(int ks=0;ks<KS;ks++){
      s16x8 ah[MF], al[MF], bh[NF], bl[NF];
      #pragma unroll
      for(int i=0;i<MF;i++){
        int row = wr*WMT+i*16+(lane&15);
        int sl = ((ks*4+kq) ^ (row&(LPR-1)))*8;
        ah[i]=*(const s16x8*)&As[row*BKT+sl];
        if constexpr (SPL) al[i]=*(const s16x8*)&As[BM*BKT+row*BKT+sl];
      }
      #pragma unroll
      for(int j=0;j<NF;j++){
        int row = wc*WNT+j*16+(lane&15);
        int sl = ((ks*4+kq) ^ (row&(LPR-1)))*8;
        bh[j]=*(const s16x8*)&Bs[row*BKT+sl];
        if constexpr (SPL) bl[j]=*(const s16x8*)&Bs[BN*BKT+row*BKT+sl];
      }
      #pragma unroll
      for(int i=0;i<MF;i++)
        #pragma unroll
        for(int j=0;j<NF;j++){
          acc[i][j]=__builtin_amdgcn_mfma_f32_16x16x32_bf16(ah[i],bh[j],acc[i][j],0,0,0);
          if constexpr (SPL){
            acc[i][j]=__builtin_amdgcn_mfma_f32_16x16x32_bf16(ah[i],bl[j],acc[i][j],0,0,0);
            acc[i][j]=__builtin_amdgcn_mfma_f32_16x16x32_bf16(al[i],bh[j],acc[i][j],0,0,0);
          }
        }
    }
  };

  if constexpr (PIPE){
    stage(0, 0);
    __syncthreads();
    for(int kt=0;kt<ktend;kt++){
      int cur = kt&1;
      if(kt+1<ktend) stage(kt+1, (cur^1)*STEP);
      compute(cur*STEP);
      __syncthreads();
    }
  } else {
    for(int kt=0;kt<ktend;kt++){
      __syncthreads();
      stage(kt, 0);
      __syncthreads();
      compute(0);
    }
  }

  if constexpr (EPI==8){
    float* C = (float*)Cp + (long)z*zC;
    #pragma unroll
    for(int i=0;i<MF;i++){
      __syncthreads();
      #pragma unroll
      for(int j=0;j<NF;j++)
        #pragma unroll
        for(int r=0;r<4;r++)
          Csf[wr*16*(BN+4) + (((lane>>4)<<2)+r)*(BN+4) + wc*WNT + j*16 + (lane&15)] = acc[i][j][r]*scale;
      __syncthreads();
      const int rrow = tid>>3;
      const int wri = rrow>>4, r16 = rrow&15;
      const long gm = m0 + wri*WMT + i*16 + r16;
      #pragma unroll
      for(int s=0;s<BN/32;s++){
        int c0 = ((tid&7) + s*8)*4;
        const float* Cr = &Csf[wri*16*(BN+4) + r16*(BN+4)];
        float4 vv = { Cr[c0], Cr[c0+1], Cr[c0+2], Cr[c0+3] };
        *(float4*)(C + gm*ldc + n0 + c0) = vv;
      }
    }
    return;
  }

  #pragma unroll
  for(int i=0;i<MF;i++){
    #pragma unroll
    for(int j=0;j<NF;j++){
      const int gm0 = m0 + wr*WMT + i*16 + ((lane>>4)<<2);
      const int gn  = n0 + wc*WNT + j*16 + (lane&15);
      #pragma unroll
      for(int r=0;r<4;r++){
        const int gm = gm0+r;
        const float v = acc[i][j][r];
        const bool live = (GATH==0) || (gm < cnt);
        if constexpr (EPI==1){
          if(live) ((float*)Cp + (long)z*zC)[(long)gm*ldc+gn] = v*scale;
        } else if constexpr (EPI==2){
          float* C = (float*)Cp; C[(long)gm*ldc+gn] += v;
        } else if constexpr (EPI==7){
          if(live) ((float*)Cp)[(long)(eid_*T_+gm)*ldc+gn] = v*scale;
        } else if constexpr (EPI==9){
          u16* Ch = (u16*)Cp + (long)z*zC;
          u16* Cl = (u16*)auxp + (long)z*zC;
          long idx = (long)gm*ldc+gn;
          u16 hv = f2b(v);
          Ch[idx]=hv; Cl[idx]=f2b(v-b2f(hv));
        }
      }
    }
  }
}

extern "C" void kernel_launch(void* const* d_in, const int* in_sizes, int n_in,
                              void* d_out, int out_size, void* d_ws, size_t ws_size,
                              hipStream_t stream)
{
  (void)in_sizes; (void)n_in; (void)out_size;
  const int*   ids   = (const int*)d_in[0];
  const float* emb   = (const float*)d_in[1];
  const float* Wq    = (const float*)d_in[2];
  const float* Wk    = (const float*)d_in[3];
  const float* Wv    = (const float*)d_in[4];
  const float* Wo    = (const float*)d_in[5];
  const float* ln1   = (const float*)d_in[6];
  const float* ln2   = (const float*)d_in[7];
  const float* gate  = (const float*)d_in[8];
  const float* Wg    = (const float*)d_in[9];
  const float* Wu    = (const float*)d_in[10];
  const float* Wd    = (const float*)d_in[11];
  const float* normw = (const float*)d_in[12];
  const float* lmh   = (const float*)d_in[13];

  char* p = (char*)d_ws;
  auto carve = [&](size_t bytes)->void*{ void* r=p; p += (bytes+255)&~(size_t)255; return r; };
  float* h    = (float*)carve((size_t)T_*H_*4);
  u16*   xhi  = (u16*)  carve((size_t)T_*H_*2);
  u16*   xlo  = (u16*)  carve((size_t)T_*H_*2);
  u16*   qhi  = (u16*)  carve((size_t)T_*NHD*2);
  u16*   qlo  = (u16*)  carve((size_t)T_*NHD*2);
  u16*   khi  = (u16*)  carve((size_t)T_*KVD*2);
  u16*   klo  = (u16*)  carve((size_t)T_*KVD*2);
  u16*   vthi = (u16*)  carve((size_t)T_*KVD*2);
  u16*   vtlo = (u16*)  carve((size_t)T_*KVD*2);
  u16*   ohi  = (u16*)  carve((size_t)T_*NHD*2);
  u16*   olo  = (u16*)  carve((size_t)T_*NHD*2);
  float* comb = (float*)carve((size_t)T_*4*4);
  int*   cnt  = (int*)  carve((size_t)16*4);
  int*   lists= (int*)  carve((size_t)4*T_*4);
  int2*  epos = (int2*) carve((size_t)T_*8);
  char*  U    = (char*) carve((size_t)112*1024*1024);
  u16*   wp   = (u16*)  carve((size_t)56623104*2);
  if ((size_t)(p - (char*)d_ws) > ws_size) return;

  u16*   guh  = (u16*)U;
  u16*   gul  = (u16*)(U + 33554432);
  float* eo   = (float*)(U + 67108864);

  u16 *WqkvTh = wp,          *WqkvTl = wp+2097152;
  u16 *WoTh = wp+4194304,    *WoTl = wp+5242880;
  u16 *WgTh = wp+6291456,    *WgTl = wp+14680064;
  u16 *WuTh = wp+23068672,   *WuTl = wp+31457280;
  u16 *WdTh = wp+39845888,   *WdTl = wp+48234496;

  dim3 tb(32,8);

  k_embed<<<T_,256,0,stream>>>(ids, emb, h, cnt);

  for(int l=0;l<4;l++){
    k_wtrans<<<27648,tb,0,stream>>>(
      Wq+(size_t)l*H_*NHD, Wk+(size_t)l*H_*KVD, Wv+(size_t)l*H_*KVD, Wo+(size_t)l*NHD*H_,
      Wg+(size_t)l*4*H_*I_, Wu+(size_t)l*4*H_*I_, Wd+(size_t)l*4*I_*H_,
      WqkvTh, WqkvTl, WoTh, WoTl, WgTh, WgTl, WuTh, WuTl, WdTh, WdTl);

    if(l==0) k_rms_sp<<<T_/4,256,0,stream>>>(h, ln1, xhi, xlo);

    k_qkv<<<dim3(16,16),256,0,stream>>>(xhi, xlo, WqkvTh, WqkvTl, qhi, qlo, khi, klo, vthi, vtlo);

    k_flash<<<dim3(8,16,2),512,0,stream>>>(qhi, qlo, khi, klo, vthi, vtlo, ohi, olo);

    k_gemm<64,128,2,2,64,true,2,0,false,false><<<dim3(32,8,1),256,0,stream>>>(
      ohi, olo, WoTh, WoTl, h, nullptr, nullptr, NHD, NHD, NHD, H_, 0,0,1,0, 0.f);

    k_router<<<T_/4,256,0,stream>>>(h, ln2+(size_t)l*H_, gate+(size_t)l*H_*4, comb, lists, cnt+l*4, epos, xhi, xlo);

    k_moe_ug<<<2048,256,0,stream>>>(xhi, xlo, WuTh, WuTl, WgTh, WgTl, guh, gul, lists, cnt+l*4);
    k_gemm<128,128,2,2,64,true,7,4,false,false><<<512,256,0,stream>>>(
      guh, gul, WdTh, WdTl, eo, nullptr, cnt+l*4, I_, I_, I_, H_, 0, (long)I_*H_, 1, 0, 1.f);
    if(l<3)
      k_combine<<<T_,256,0,stream>>>(h, eo, epos, comb, ln1+(size_t)(l+1)*H_, xhi, xlo);
    else
      k_combine<<<T_,256,0,stream>>>(h, eo, epos, comb, normw, xhi, nullptr);
  }

  k_transpose<<<dim3(1000,32),tb,0,stream>>>(lmh, wp, nullptr, H_, V_, 0,0);
  // lm_head: single-plane A, BK=64 swizzled, XCD swizzle, 2-phase PIPE (64KB smem-union, 2 blocks/CU)
  k_gemm<128,128,2,2,64,false,8,0,true,true><<<dim3(16,250,1),256,0,stream>>>(
    xhi, nullptr, wp, nullptr, (float*)d_out, nullptr, nullptr, H_, H_, H_, V_, 0,0,1,0, 1.f);
}

// Round 20
// 1827.950 us; speedup vs baseline: 1.0163x; 1.0163x over previous
//
#include <hip/hip_runtime.h>

#define T_ 2048
#define H_ 1024
#define S_ 1024
#define V_ 32000
#define I_ 2048
#define NHD 1024   // NH*HD
#define KVD 512    // NKV*HD

typedef unsigned short u16;
typedef unsigned int u32;
typedef __attribute__((ext_vector_type(8))) short s16x8;
typedef __attribute__((ext_vector_type(4))) float f32x4;

__device__ __forceinline__ u16 f2b(float f){ u32 x=__builtin_bit_cast(u32,f); return (u16)((x+0x7fffu+((x>>16)&1u))>>16); }
__device__ __forceinline__ float b2f(u16 u){ return __builtin_bit_cast(float,(u32)u<<16); }
__device__ __forceinline__ float wsum(float v){ for(int o=32;o;o>>=1) v+=__shfl_xor(v,o); return v; }

// async global->LDS, 16B per lane; LDS dest = wave-uniform base + lane*16
__device__ __forceinline__ void gl16(const void* g, void* l){
  __builtin_amdgcn_global_load_lds(
      (const __attribute__((address_space(1))) unsigned int*)g,
      (__attribute__((address_space(3))) unsigned int*)l, 16, 0, 0);
}

// ---------------- embedding gather (+ expert counter zero) ----------------
__global__ void k_embed(const int* __restrict__ ids, const float* __restrict__ emb,
                        float* __restrict__ h, int* __restrict__ cnt){
  if(blockIdx.x==0 && threadIdx.x<16) cnt[threadIdx.x]=0;
  int t = blockIdx.x;
  long src = (long)ids[t]*H_;
  ((float4*)(h + (long)t*H_))[threadIdx.x] = ((const float4*)(emb+src))[threadIdx.x];
}

// ---------------- rmsnorm: fp32 -> bf16 hi(/lo) planes ----------------
__global__ void k_rms_sp(const float* __restrict__ h, const float* __restrict__ w,
                         u16* __restrict__ xhi, u16* __restrict__ xlo){
  int wid = threadIdx.x>>6, lane = threadIdx.x&63;
  int t = blockIdx.x*4 + wid;
  const float* row = h + (long)t*H_;
  float v[16]; float ss=0.f;
  #pragma unroll
  for(int j=0;j<16;j++){ v[j]=row[j*64+lane]; ss += v[j]*v[j]; }
  ss = wsum(ss);
  float rstd = rsqrtf(ss/(float)H_ + 1e-6f);
  #pragma unroll
  for(int j=0;j<16;j++){
    int idx=j*64+lane;
    float y = v[j]*rstd*w[idx];
    u16 hv = f2b(y);
    xhi[(long)t*H_+idx] = hv;
    if(xlo) xlo[(long)t*H_+idx] = f2b(y - b2f(hv));
  }
}

// ---------------- router (fp32) + expert list build + ln2 planes (merged) ----------------
__global__ void k_router(const float* __restrict__ h, const float* __restrict__ lw,
                         const float* __restrict__ gate, float* __restrict__ comb,
                         int* __restrict__ lists, int* __restrict__ cnt, int2* __restrict__ epos,
                         u16* __restrict__ xhi, u16* __restrict__ xlo){
  int wid = threadIdx.x>>6, lane = threadIdx.x&63;
  int t = blockIdx.x*4+wid;
  const float* row = h + (long)t*H_;
  float v[16]; float ss=0.f;
  #pragma unroll
  for(int j=0;j<16;j++){ v[j]=row[j*64+lane]; ss+=v[j]*v[j]; }
  ss = wsum(ss);
  float rstd = rsqrtf(ss/(float)H_+1e-6f);
  float a0=0,a1=0,a2=0,a3=0;
  #pragma unroll
  for(int j=0;j<16;j++){
    int idx=j*64+lane;
    float y = v[j]*rstd*lw[idx];
    u16 hv = f2b(y);
    xhi[(long)t*H_+idx] = hv;
    xlo[(long)t*H_+idx] = f2b(y - b2f(hv));
    float4 g4 = ((const float4*)gate)[idx];
    a0 += y*g4.x; a1 += y*g4.y; a2 += y*g4.z; a3 += y*g4.w;
  }
  a0=wsum(a0); a1=wsum(a1); a2=wsum(a2); a3=wsum(a3);
  if(lane==0){
    float p[4]={a0,a1,a2,a3};
    float m = fmaxf(fmaxf(p[0],p[1]),fmaxf(p[2],p[3]));
    float s=0; for(int e=0;e<4;e++){ p[e]=__expf(p[e]-m); s+=p[e]; }
    for(int e=0;e<4;e++) p[e]/=s;
    int i1=0; for(int e=1;e<4;e++) if(p[e]>p[i1]) i1=e;
    int i2=-1; for(int e=0;e<4;e++){ if(e==i1) continue; if(i2<0||p[e]>p[i2]) i2=e; }
    float* c = comb + (long)t*4;
    for(int e=0;e<4;e++) c[e] = (e==i1||e==i2)? p[e] : 0.f;
    int p1 = atomicAdd(&cnt[i1],1); lists[i1*T_+p1]=t;
    int p2 = atomicAdd(&cnt[i2],1); lists[i2*T_+p2]=t;
    epos[t] = make_int2((p1<<2)|i1, (p2<<2)|i2);
  }
}

// ---------------- transpose+split: fp32 [R][C] -> bf16 hi(+lo) [C][R] ----------------
__global__ void k_transpose(const float* __restrict__ in, u16* __restrict__ hi, u16* __restrict__ lo,
                            int R, int C, long zi, long zo){
  __shared__ float tile[32][33];
  in += (long)blockIdx.z*zi; hi += (long)blockIdx.z*zo; if(lo) lo += (long)blockIdx.z*zo;
  int c0 = blockIdx.x*32, r0 = blockIdx.y*32;
  int tx = threadIdx.x, ty = threadIdx.y;
  #pragma unroll
  for(int i=0;i<4;i++) tile[ty+8*i][tx] = in[(long)(r0+ty+8*i)*C + c0+tx];
  __syncthreads();
  #pragma unroll
  for(int i=0;i<4;i++){
    int cc=ty+8*i; float v = tile[tx][cc];
    u16 hv = f2b(v);
    long idx = (long)(c0+cc)*R + r0+tx;
    hi[idx] = hv;
    if(lo) lo[idx] = f2b(v - b2f(hv));
  }
}

// ---------------- all per-layer weight transposes in ONE launch ----------------
__global__ void k_wtrans(const float* __restrict__ Wq, const float* __restrict__ Wk,
                         const float* __restrict__ Wv, const float* __restrict__ Wo,
                         const float* __restrict__ Wg, const float* __restrict__ Wu,
                         const float* __restrict__ Wd,
                         u16* __restrict__ qkvh, u16* __restrict__ qkvl,
                         u16* __restrict__ oh, u16* __restrict__ ol,
                         u16* __restrict__ gh, u16* __restrict__ gl_,
                         u16* __restrict__ uh, u16* __restrict__ ul,
                         u16* __restrict__ dh, u16* __restrict__ dl)
{
  __shared__ float tile[32][33];
  int id = blockIdx.x;
  const float* in; u16 *hi, *lo; int R, C, bx, by;
  if(id < 1024){ in=Wq; hi=qkvh; lo=qkvl; R=1024; C=1024; bx=id&31; by=id>>5; }
  else if(id < 1536){ id-=1024; in=Wk; hi=qkvh+1048576; lo=qkvl+1048576; R=1024; C=512; bx=id&15; by=id>>4; }
  else if(id < 2048){ id-=1536; in=Wv; hi=qkvh+1572864; lo=qkvl+1572864; R=1024; C=512; bx=id&15; by=id>>4; }
  else if(id < 3072){ id-=2048; in=Wo; hi=oh; lo=ol; R=1024; C=1024; bx=id&31; by=id>>5; }
  else if(id < 11264){ id-=3072; int z=id>>11, r2=id&2047;
    in=Wg+(size_t)z*H_*I_; hi=gh+(size_t)z*I_*H_; lo=gl_+(size_t)z*I_*H_;
    R=1024; C=2048; bx=r2&63; by=r2>>6; }
  else if(id < 19456){ id-=11264; int z=id>>11, r2=id&2047;
    in=Wu+(size_t)z*H_*I_; hi=uh+(size_t)z*I_*H_; lo=ul+(size_t)z*I_*H_;
    R=1024; C=2048; bx=r2&63; by=r2>>6; }
  else { id-=19456; int z=id>>11, r2=id&2047;
    in=Wd+(size_t)z*I_*H_; hi=dh+(size_t)z*H_*I_; lo=dl+(size_t)z*H_*I_;
    R=2048; C=1024; bx=r2&31; by=r2>>5; }
  int c0=bx*32, r0=by*32, tx=threadIdx.x, ty=threadIdx.y;
  #pragma unroll
  for(int i=0;i<4;i++) tile[ty+8*i][tx] = in[(long)(r0+ty+8*i)*C + c0+tx];
  __syncthreads();
  #pragma unroll
  for(int i=0;i<4;i++){
    int cc=ty+8*i; float v = tile[tx][cc];
    u16 hv = f2b(v);
    long idx = (long)(c0+cc)*R + r0+tx;
    hi[idx] = hv;
    lo[idx] = f2b(v - b2f(hv));
  }
}

// ---------------- MoE combine + fused next-layer rmsnorm planes ----------------
__global__ void k_combine(float* __restrict__ h, const float* __restrict__ eo,
                          const int2* __restrict__ epos, const float* __restrict__ comb,
                          const float* __restrict__ wn, u16* __restrict__ xhi, u16* __restrict__ xlo){
  int t = blockIdx.x, c = threadIdx.x;
  int lane = c&63, wid = c>>6;
  int2 ep = epos[t];
  int e1 = ep.x&3, p1 = ep.x>>2, e2 = ep.y&3, p2 = ep.y>>2;
  float c1 = comb[t*4+e1], c2 = comb[t*4+e2];
  float4 a = ((const float4*)(eo + (long)(e1*T_+p1)*H_))[c];
  float4 b = ((const float4*)(eo + (long)(e2*T_+p2)*H_))[c];
  float4* hp = (float4*)(h + (long)t*H_) + c;
  float4 hv = *hp;
  hv.x += c1*a.x + c2*b.x; hv.y += c1*a.y + c2*b.y;
  hv.z += c1*a.z + c2*b.z; hv.w += c1*a.w + c2*b.w;
  *hp = hv;
  __shared__ float red[4];
  float ss = hv.x*hv.x + hv.y*hv.y + hv.z*hv.z + hv.w*hv.w;
  ss = wsum(ss);
  if(lane==0) red[wid]=ss;
  __syncthreads();
  float tot = red[0]+red[1]+red[2]+red[3];
  float rstd = rsqrtf(tot*(1.f/1024.f) + 1e-6f);
  float4 wv = ((const float4*)wn)[c];
  float y0=hv.x*rstd*wv.x, y1=hv.y*rstd*wv.y, y2=hv.z*rstd*wv.z, y3=hv.w*rstd*wv.w;
  ushort4 Hv; Hv.x=f2b(y0); Hv.y=f2b(y1); Hv.z=f2b(y2); Hv.w=f2b(y3);
  ((ushort4*)(xhi + (long)t*H_))[c] = Hv;
  if(xlo){
    ushort4 Lv;
    Lv.x=f2b(y0-b2f(Hv.x)); Lv.y=f2b(y1-b2f(Hv.y));
    Lv.z=f2b(y2-b2f(Hv.z)); Lv.w=f2b(y3-b2f(Hv.w));
    ((ushort4*)(xlo + (long)t*H_))[c] = Lv;
  }
}

// ---------------- fused flash attention (QBLK=128, 8 waves, co-staged K/V, 2 barriers/tile) ----------------
__global__ __launch_bounds__(512) void k_flash(
  const u16* __restrict__ qh_g, const u16* __restrict__ ql_g,
  const u16* __restrict__ kh_g, const u16* __restrict__ kl_g,
  const u16* __restrict__ vth_g, const u16* __restrict__ vtl_g,
  u16* __restrict__ oh_g, u16* __restrict__ ol_g)
{
  __shared__ alignas(16) u16 Kh[8192], Kl[8192];
  __shared__ alignas(16) u16 Vh[8192], Vl[8192];
  __shared__ alignas(16) u16 Ph[16384], Pl[16384];
  const int qt = blockIdx.x, hh = blockIdx.y, b = blockIdx.z;
  const int hk = hh>>1;
  const int lane = threadIdx.x&63, w = threadIdx.x>>6;
  const int rA = lane&15, kg = (lane>>4)*8;

  s16x8 qfh[2], qfl[2];
  {
    long t = (long)(b*1024+qt*128) + w*16 + rA;
    const u16* qp = qh_g + t*NHD + hh*64;
    const u16* qp2= ql_g + t*NHD + hh*64;
    qfh[0]=*(const s16x8*)(qp + kg);      qfh[1]=*(const s16x8*)(qp + 32 + kg);
    qfl[0]=*(const s16x8*)(qp2 + kg);     qfl[1]=*(const s16x8*)(qp2 + 32 + kg);
  }

  const int ktend = qt+1;
  {
    const u16* kp = kh_g + ((long)(b*1024))*KVD + hk*64;
    const u16* kp2= kl_g + ((long)(b*1024))*KVD + hk*64;
    #pragma unroll
    for(int s=0;s<2;s++){
      int idx=s*8+w, hf=idx>>3, g=idx&7;
      int row = g*16 + (lane>>2);
      int c8  = hf*32 + (lane&3)*8;
      gl16(kp  + (long)row*KVD + c8, &Kh[hf*4096 + g*512]);
      gl16(kp2 + (long)row*KVD + c8, &Kl[hf*4096 + g*512]);
    }
  }

  f32x4 Oa[4];
  float mrun[4], lrun[4];
  #pragma unroll
  for(int jn=0;jn<4;jn++){ f32x4 zv={0.f,0.f,0.f,0.f}; Oa[jn]=zv; }
  #pragma unroll
  for(int r=0;r<4;r++){ mrun[r]=-3.0e38f; lrun[r]=0.f; }

  __syncthreads();

  for(int kt=0; kt<ktend; kt++){
    {
      const u16* vp = vth_g + (long)b*((long)KVD*S_) + (long)(hk*64)*S_ + kt*128;
      const u16* vp2= vtl_g + (long)b*((long)KVD*S_) + (long)(hk*64)*S_ + kt*128;
      #pragma unroll
      for(int s=0;s<2;s++){
        int idx=s*8+w, ks=idx>>2, g=idx&3;
        int dr = g*16 + (lane>>2);
        int k8 = (lane&3)*8;
        gl16(vp  + (long)dr*S_ + ks*32 + k8, &Vh[ks*2048 + g*512]);
        gl16(vp2 + (long)dr*S_ + ks*32 + k8, &Vl[ks*2048 + g*512]);
      }
    }

    f32x4 Sf[8];
    #pragma unroll
    for(int j=0;j<8;j++){ f32x4 zv={0.f,0.f,0.f,0.f}; Sf[j]=zv; }
    #pragma unroll
    for(int k2=0;k2<2;k2++){
      s16x8 bh[8],bl[8];
      #pragma unroll
      for(int j=0;j<8;j++){
        int ky = j*16+rA;
        bh[j]=*(const s16x8*)&Kh[k2*4096 + ky*32 + kg];
        bl[j]=*(const s16x8*)&Kl[k2*4096 + ky*32 + kg];
      }
      #pragma unroll
      for(int j=0;j<8;j++){
        Sf[j]=__builtin_amdgcn_mfma_f32_16x16x32_bf16(qfh[k2],bh[j],Sf[j],0,0,0);
        Sf[j]=__builtin_amdgcn_mfma_f32_16x16x32_bf16(qfh[k2],bl[j],Sf[j],0,0,0);
        Sf[j]=__builtin_amdgcn_mfma_f32_16x16x32_bf16(qfl[k2],bh[j],Sf[j],0,0,0);
      }
    }

    const bool last = (kt==ktend-1);
    #pragma unroll
    for(int j=0;j<8;j++)
      #pragma unroll
      for(int r=0;r<4;r++){
        float sv = Sf[j][r]*0.125f;
        if(last){
          int qr = qt*128 + w*16 + ((lane>>4)<<2) + r;
          int ky = kt*128 + j*16 + (lane&15);
          if(ky>qr) sv = -3.0e38f;
        }
        Sf[j][r]=sv;
      }

    float mt[4];
    #pragma unroll
    for(int r=0;r<4;r++){
      float v = Sf[0][r];
      #pragma unroll
      for(int j=1;j<8;j++) v = fmaxf(v, Sf[j][r]);
      v=fmaxf(v,__shfl_xor(v,1)); v=fmaxf(v,__shfl_xor(v,2));
      v=fmaxf(v,__shfl_xor(v,4)); v=fmaxf(v,__shfl_xor(v,8));
      mt[r]=v;
    }

    #pragma unroll
    for(int r=0;r<4;r++){
      float mo=mrun[r];
      float mn=fmaxf(mo,mt[r]);
      float al_=__expf(mo-mn);
      mrun[r]=mn;
      lrun[r]*=al_;
      #pragma unroll
      for(int jn=0;jn<4;jn++) Oa[jn][r]*=al_;
    }

    float ls[4];
    #pragma unroll
    for(int r=0;r<4;r++) ls[r]=0.f;
    #pragma unroll
    for(int j=0;j<8;j++)
      #pragma unroll
      for(int r=0;r<4;r++){
        int q  = w*16+((lane>>4)<<2)+r;
        int ky = j*16+(lane&15);
        float pv=__expf(Sf[j][r]-mrun[r]);
        ls[r]+=pv;
        u16 hv=f2b(pv);
        int a=(ky>>5)*4096 + q*32 + (ky&31);
        Ph[a]=hv; Pl[a]=f2b(pv-b2f(hv));
      }
    #pragma unroll
    for(int r=0;r<4;r++){
      float v=ls[r];
      v+=__shfl_xor(v,1); v+=__shfl_xor(v,2); v+=__shfl_xor(v,4); v+=__shfl_xor(v,8);
      lrun[r]+=v;
    }
    __syncthreads();

    if(kt+1<ktend){
      const u16* kp = kh_g + ((long)(b*1024+(kt+1)*128))*KVD + hk*64;
      const u16* kp2= kl_g + ((long)(b*1024+(kt+1)*128))*KVD + hk*64;
      #pragma unroll
      for(int s=0;s<2;s++){
        int idx=s*8+w, hf=idx>>3, g=idx&7;
        int row = g*16 + (lane>>2);
        int c8  = hf*32 + (lane&3)*8;
        gl16(kp  + (long)row*KVD + c8, &Kh[hf*4096 + g*512]);
        gl16(kp2 + (long)row*KVD + c8, &Kl[hf*4096 + g*512]);
      }
    }

    #pragma unroll
    for(int ks=0;ks<4;ks++){
      s16x8 pah,pal,vbh[4],vbl[4];
      int q = w*16+rA;
      pah=*(const s16x8*)&Ph[ks*4096 + q*32 + kg];
      pal=*(const s16x8*)&Pl[ks*4096 + q*32 + kg];
      #pragma unroll
      for(int jn=0;jn<4;jn++){
        int d = jn*16+rA;
        vbh[jn]=*(const s16x8*)&Vh[ks*2048 + d*32 + kg];
        vbl[jn]=*(const s16x8*)&Vl[ks*2048 + d*32 + kg];
      }
      #pragma unroll
      for(int jn=0;jn<4;jn++){
        Oa[jn]=__builtin_amdgcn_mfma_f32_16x16x32_bf16(pah,vbh[jn],Oa[jn],0,0,0);
        Oa[jn]=__builtin_amdgcn_mfma_f32_16x16x32_bf16(pah,vbl[jn],Oa[jn],0,0,0);
        Oa[jn]=__builtin_amdgcn_mfma_f32_16x16x32_bf16(pal,vbh[jn],Oa[jn],0,0,0);
      }
    }
    __syncthreads();
  }

  #pragma unroll
  for(int jn=0;jn<4;jn++)
    #pragma unroll
    for(int r=0;r<4;r++){
      long t = (long)b*1024 + qt*128 + w*16+((lane>>4)<<2)+r;
      int col = hh*64 + jn*16 + (lane&15);
      float ov = Oa[jn][r] / lrun[r];
      u16 hv=f2b(ov);
      oh_g[t*NHD+col]=hv;
      ol_g[t*NHD+col]=f2b(ov-b2f(hv));
    }
}

// ---------------- fused QKV GEMM (gload staging, BK=64, swizzled LDS) ----------------
__global__ __launch_bounds__(256) void k_qkv(
  const u16* __restrict__ xhi, const u16* __restrict__ xlo,
  const u16* __restrict__ Bh, const u16* __restrict__ Bl,
  u16* __restrict__ qhi, u16* __restrict__ qlo,
  u16* __restrict__ khi, u16* __restrict__ klo,
  u16* __restrict__ vthi, u16* __restrict__ vtlo)
{
  __shared__ alignas(16) u16 As[2*128*64], Bs[2*128*64];
  const int m0=blockIdx.x*128, n0=blockIdx.y*128;
  const int tid=threadIdx.x, lane=tid&63, w=tid>>6, wr=w>>1, wc=w&1;
  const int rsub = lane>>3;
  const int col8 = ((lane&7) ^ (rsub&7))*8;
  const int kq = lane>>4;
  f32x4 acc[4][4];
  #pragma unroll
  for(int i=0;i<4;i++)
    #pragma unroll
    for(int j=0;j<4;j++){ f32x4 zv={0.f,0.f,0.f,0.f}; acc[i][j]=zv; }

  for(int kt=0;kt<16;kt++){
    const int k0=kt*64;
    __syncthreads();
    #pragma unroll
    for(int s=0;s<4;s++){
      int ch=s*4+w; int row=ch*8+rsub;
      gl16(xhi + (long)(m0+row)*H_ + k0+col8, &As[ch*512]);
      gl16(xlo + (long)(m0+row)*H_ + k0+col8, &As[8192+ch*512]);
      gl16(Bh  + (long)(n0+row)*H_ + k0+col8, &Bs[ch*512]);
      gl16(Bl  + (long)(n0+row)*H_ + k0+col8, &Bs[8192+ch*512]);
    }
    __syncthreads();
    #pragma unroll
    for(int ks=0;ks<2;ks++){
      s16x8 ah[4],al[4],bh[4],bl[4];
      #pragma unroll
      for(int i=0;i<4;i++){
        int row = wr*64+i*16+(lane&15);
        int sl = ((ks*4+kq) ^ (row&7))*8;
        ah[i]=*(const s16x8*)&As[row*64+sl];
        al[i]=*(const s16x8*)&As[8192+row*64+sl];
      }
      #pragma unroll
      for(int j=0;j<4;j++){
        int row = wc*64+j*16+(lane&15);
        int sl = ((ks*4+kq) ^ (row&7))*8;
        bh[j]=*(const s16x8*)&Bs[row*64+sl];
        bl[j]=*(const s16x8*)&Bs[8192+row*64+sl];
      }
      #pragma unroll
      for(int i=0;i<4;i++)
        #pragma unroll
        for(int j=0;j<4;j++){
          acc[i][j]=__builtin_amdgcn_mfma_f32_16x16x32_bf16(ah[i],bh[j],acc[i][j],0,0,0);
          acc[i][j]=__builtin_amdgcn_mfma_f32_16x16x32_bf16(ah[i],bl[j],acc[i][j],0,0,0);
          acc[i][j]=__builtin_amdgcn_mfma_f32_16x16x32_bf16(al[i],bh[j],acc[i][j],0,0,0);
        }
    }
  }

  #pragma unroll
  for(int i=0;i<4;i++){
    #pragma unroll
    for(int j=0;j<4;j++){
      const int gm0 = m0 + wr*64 + i*16 + ((lane>>4)<<2);
      const int gn  = n0 + wc*64 + j*16 + (lane&15);
      #pragma unroll
      for(int r=0;r<4;r++){
        const int gm = gm0+r;
        float v = acc[i][j][r];
        u16 hv = f2b(v);
        u16 lv = f2b(v - b2f(hv));
        if(gn < 1024){
          long idx=(long)gm*NHD+gn; qhi[idx]=hv; qlo[idx]=lv;
        } else if(gn < 1536){
          long idx=(long)gm*KVD+(gn-1024); khi[idx]=hv; klo[idx]=lv;
        } else {
          long idx=((long)(gm>>10)<<19) + (long)(gn-1536)*S_ + (gm&1023);
          vthi[idx]=hv; vtlo[idx]=lv;
        }
      }
    }
  }
}

// ---------------- fused MoE up+gate (gload, BK=64, swizzled, XCD-grouped 1D grid) ----------------
__global__ __launch_bounds__(256) void k_moe_ug(
  const u16* __restrict__ xhi, const u16* __restrict__ xlo,
  const u16* __restrict__ Wuh, const u16* __restrict__ Wul,
  const u16* __restrict__ Wgh, const u16* __restrict__ Wgl,
  u16* __restrict__ guh, u16* __restrict__ gul,
  const int* __restrict__ lists, const int* __restrict__ cntp)
{
  const int bb = blockIdx.x;
  const int xcd = bb&7, bidx = bb>>3;
  const int grp = xcd + 8*(bidx>>4);
  const int mslot = bidx&15;
  const int e = grp>>5;
  const int n0 = (grp&31)*64;
  const int m0 = mslot*128;
  const int ce = cntp[e];
  if(m0>=ce) return;
  const int* ridx = lists + e*T_;
  const u16* Buh_g = Wuh + (size_t)e*H_*I_;
  const u16* Bul_g = Wul + (size_t)e*H_*I_;
  const u16* Bgh_g = Wgh + (size_t)e*H_*I_;
  const u16* Bgl_g = Wgl + (size_t)e*H_*I_;
  __shared__ alignas(16) u16 Ah[128*64], Al[128*64];
  __shared__ alignas(16) u16 Buh[64*64], Bul[64*64], Bgh[64*64], Bgl[64*64];
  const int tid=threadIdx.x, lane=tid&63, w=tid>>6;
  const int wr=w>>1, wc=w&1;
  const int rsub = lane>>3;
  const int col8 = ((lane&7) ^ (rsub&7))*8;
  const int kq = lane>>4;
  int arA[4];
  #pragma unroll
  for(int s=0;s<4;s++){ int idx=m0 + (s*4+w)*8 + rsub; arA[s]=ridx[idx<ce?idx:ce-1]; }
  f32x4 au[4][2], ag[4][2];
  #pragma unroll
  for(int i=0;i<4;i++)
    #pragma unroll
    for(int j=0;j<2;j++){ f32x4 zv={0.f,0.f,0.f,0.f}; au[i][j]=zv; ag[i][j]=zv; }

  for(int kt=0;kt<16;kt++){
    const int k0=kt*64;
    __syncthreads();
    #pragma unroll
    for(int s=0;s<4;s++){
      int ch=s*4+w;
      gl16(xhi + (long)arA[s]*H_ + k0+col8, &Ah[ch*512]);
      gl16(xlo + (long)arA[s]*H_ + k0+col8, &Al[ch*512]);
    }
    #pragma unroll
    for(int s=0;s<2;s++){
      int ch=s*4+w;
      int brow = n0 + ch*8 + rsub;
      gl16(Buh_g + (long)brow*H_ + k0+col8, &Buh[ch*512]);
      gl16(Bul_g + (long)brow*H_ + k0+col8, &Bul[ch*512]);
      gl16(Bgh_g + (long)brow*H_ + k0+col8, &Bgh[ch*512]);
      gl16(Bgl_g + (long)brow*H_ + k0+col8, &Bgl[ch*512]);
    }
    __syncthreads();
    #pragma unroll
    for(int ks=0;ks<2;ks++){
      s16x8 fah[4],fal[4],fbuh[2],fbul[2],fbgh[2],fbgl[2];
      #pragma unroll
      for(int i=0;i<4;i++){
        int row = wr*64+i*16+(lane&15);
        int sl = ((ks*4+kq) ^ (row&7))*8;
        fah[i]=*(const s16x8*)&Ah[row*64+sl];
        fal[i]=*(const s16x8*)&Al[row*64+sl];
      }
      #pragma unroll
      for(int j=0;j<2;j++){
        int row = wc*32+j*16+(lane&15);
        int sl = ((ks*4+kq) ^ (row&7))*8;
        fbuh[j]=*(const s16x8*)&Buh[row*64+sl];
        fbul[j]=*(const s16x8*)&Bul[row*64+sl];
        fbgh[j]=*(const s16x8*)&Bgh[row*64+sl];
        fbgl[j]=*(const s16x8*)&Bgl[row*64+sl];
      }
      #pragma unroll
      for(int i=0;i<4;i++)
        #pragma unroll
        for(int j=0;j<2;j++){
          au[i][j]=__builtin_amdgcn_mfma_f32_16x16x32_bf16(fah[i],fbuh[j],au[i][j],0,0,0);
          au[i][j]=__builtin_amdgcn_mfma_f32_16x16x32_bf16(fah[i],fbul[j],au[i][j],0,0,0);
          au[i][j]=__builtin_amdgcn_mfma_f32_16x16x32_bf16(fal[i],fbuh[j],au[i][j],0,0,0);
          ag[i][j]=__builtin_amdgcn_mfma_f32_16x16x32_bf16(fah[i],fbgh[j],ag[i][j],0,0,0);
          ag[i][j]=__builtin_amdgcn_mfma_f32_16x16x32_bf16(fah[i],fbgl[j],ag[i][j],0,0,0);
          ag[i][j]=__builtin_amdgcn_mfma_f32_16x16x32_bf16(fal[i],fbgh[j],ag[i][j],0,0,0);
        }
    }
  }

  #pragma unroll
  for(int i=0;i<4;i++){
    #pragma unroll
    for(int j=0;j<2;j++){
      const int gm0 = m0 + wr*64 + i*16 + ((lane>>4)<<2);
      const int gn  = n0 + wc*32 + j*16 + (lane&15);
      #pragma unroll
      for(int r=0;r<4;r++){
        const int gm = gm0+r;
        if(gm<ce){
          float uu=au[i][j][r], gg=ag[i][j][r];
          float val = (gg/(1.f+__expf(-gg)))*uu;
          long idx = (long)(e*T_+gm)*I_ + gn;
          u16 hv=f2b(val);
          guh[idx]=hv; gul[idx]=f2b(val-b2f(hv));
        }
      }
    }
  }
}

// ---------------- lm_head: 256x256 tile, BK=64, 8 waves, counted-vmcnt 2-barrier schedule ----------------
// grid 1000 (1-D, XCD-bijective). LDS 128KB: A[2][256x64] + B[2][256x64] bf16.
__global__ __launch_bounds__(512) void k_lmhead(
  const u16* __restrict__ A, const u16* __restrict__ B, float* __restrict__ C)
{
  __shared__ alignas(16) u16 smem[65536];   // 128KB
  const int bb = blockIdx.x;
  const int wid = (bb&7)*125 + (bb>>3);     // bijective: 1000%8==0
  const int m0 = (wid&7)*256;
  const int n0 = (wid>>3)*256;
  const int tid = threadIdx.x, lane = tid&63, w = tid>>6;   // w 0..7
  const int wr = w>>2, wc = w&3;            // 2M x 4N waves
  const int rsub = lane>>3;
  const int col8 = ((lane&7) ^ rsub)*8;     // inverse-swizzled source column (LPR=8)
  const int kq = lane>>4;

  f32x4 acc[8][4];
  #pragma unroll
  for(int i=0;i<8;i++)
    #pragma unroll
    for(int j=0;j<4;j++){ f32x4 zv={0.f,0.f,0.f,0.f}; acc[i][j]=zv; }

  // stage ALL of K-tile kt into dbuf c: 8 gl16 per lane
  auto stage4 = [&](int kt, int c){
    const int k0 = kt*64;
    #pragma unroll
    for(int q=0;q<4;q++){
      const u16* src = (q<2) ? A : B;
      u16* dst = &smem[(q<2 ? 0 : 32768) + c*16384 + (q&1)*8192];
      const long row0 = ((q<2) ? m0 : n0) + (q&1)*128;
      #pragma unroll
      for(int s=0;s<2;s++){
        int ch = s*8 + w;
        long row = row0 + ch*8 + rsub;
        gl16(src + row*H_ + k0 + col8, dst + ch*512);
      }
    }
  };

  stage4(0, 0);   // prologue

  for(int kt=0;kt<16;kt++){
    const int c = kt&1;
    __builtin_amdgcn_s_barrier();           // A: all waves done reading buf c^1 (prev tile)
    __builtin_amdgcn_sched_barrier(0);
    if(kt<15) stage4(kt+1, c^1);            // 8 loads fly across this tile's compute
    __builtin_amdgcn_sched_barrier(0);
    if(kt<15) asm volatile("s_waitcnt vmcnt(8)" ::: "memory");  // own tile-kt loads done
    else      asm volatile("s_waitcnt vmcnt(0)" ::: "memory");
    __builtin_amdgcn_sched_barrier(0);
    __builtin_amdgcn_s_barrier();           // B: ALL waves' tile-kt loads visible
    __builtin_amdgcn_sched_barrier(0);
    #pragma unroll
    for(int p=0;p<4;p++){
      const int ks = p>>1, ih = p&1;
      s16x8 af[4], bf[4];
      #pragma unroll
      for(int ii=0;ii<4;ii++){
        int row = wr*128 + (ih*4+ii)*16 + (lane&15);
        int sl = ((ks*4+kq) ^ (row&7))*8;
        af[ii] = *(const s16x8*)&smem[c*16384 + row*64 + sl];
      }
      #pragma unroll
      for(int j=0;j<4;j++){
        int row = wc*64 + j*16 + (lane&15);
        int sl = ((ks*4+kq) ^ (row&7))*8;
        bf[j] = *(const s16x8*)&smem[32768 + c*16384 + row*64 + sl];
      }
      __builtin_amdgcn_s_setprio(1);
      #pragma unroll
      for(int ii=0;ii<4;ii++)
        #pragma unroll
        for(int j=0;j<4;j++)
          acc[ih*4+ii][j] = __builtin_amdgcn_mfma_f32_16x16x32_bf16(af[ii], bf[j], acc[ih*4+ii][j], 0,0,0);
      __builtin_amdgcn_s_setprio(0);
    }
  }

  // epilogue: coalesced f32 stores via LDS (aliases stage buffers behind barriers)
  float* Csf = (float*)smem;
  #pragma unroll
  for(int i=0;i<8;i++){
    __syncthreads();
    #pragma unroll
    for(int j=0;j<4;j++)
      #pragma unroll
      for(int r=0;r<4;r++)
        Csf[wr*4160 + (((lane>>4)<<2)+r)*260 + wc*64 + j*16 + (lane&15)] = acc[i][j][r];
    __syncthreads();
    const int rrow = tid>>4;                 // 0..31
    const int wri = rrow>>4, r16 = rrow&15;
    const long gm = m0 + wri*128 + i*16 + r16;
    #pragma unroll
    for(int s=0;s<4;s++){
      int c0 = ((tid&15) + s*16)*4;
      const float* Cr = &Csf[wri*4160 + r16*260];
      float4 vv = { Cr[c0], Cr[c0+1], Cr[c0+2], Cr[c0+3] };
      *(float4*)(C + gm*(long)V_ + n0 + c0) = vv;
    }
  }
}

// ---------------- generic MFMA GEMM (gload + two-sided swizzle; smem-union) ----------------
template<int BM,int BN,int WM,int WN,int BKT,bool SPL,int EPI,int GATH,bool SWZ,bool PIPE>
__launch_bounds__(WM*WN*64)
__global__ void k_gemm(const u16* __restrict__ Ahip, const u16* __restrict__ Alop,
                       const u16* __restrict__ Bhip, const u16* __restrict__ Blop,
                       void* __restrict__ Cp, void* __restrict__ auxp,
                       const int* __restrict__ cntp,
                       int Kdim, int lda, int ldb, int ldc,
                       long zA, long zB, int zBdiv, long zC,
                       float scale)
{
  constexpr int NT = WM*WN*64;
  constexpr int Wv = NT/64;
  constexpr int WMT = BM/WM, WNT = BN/WN;
  constexpr int MF = WMT/16, NF = WNT/16;
  constexpr int LPR = BKT/8;
  constexpr int LR  = 64/LPR;
  constexpr int ACn = (BM/LR)/Wv;
  constexpr int BCn = (BN/LR)/Wv;
  constexpr int KS  = BKT/32;
  constexpr int ABY = (SPL?2:1)*BM*BKT*2;
  constexpr int BBY = (SPL?2:1)*BN*BKT*2;
  constexpr int STEP = ABY+BBY;
  constexpr int SBY = (PIPE?2:1)*STEP;
  constexpr int CBY = (EPI==8) ? WM*16*(BN+4)*4 : 0;
  constexpr int SMB = SBY > CBY ? SBY : CBY;
  static_assert(ACn>=1 && BCn>=1, "chunks");
  __shared__ alignas(16) char smem[SMB];
  float* Csf = (float*)smem;
  constexpr int SL = T_/BM;
  int m0, n0, eid_ = 0, cnt = 0;
  if constexpr (GATH==4){
    constexpr int NTN = H_/BN;
    const int bb = blockIdx.x;
    const int xcd = bb&7, bidx = bb>>3;
    const int grp = xcd + 8*(bidx/SL);
    const int mslot = bidx%SL;
    eid_ = grp/NTN; n0 = (grp%NTN)*BN; m0 = mslot*BM;
    cnt = cntp[eid_]; if(m0>=cnt) return;
  } else if constexpr (SWZ){
    int nx = gridDim.x;
    int l = blockIdx.y*nx + blockIdx.x;
    int q = (nx*gridDim.y)>>3;
    int wid = (l&7)*q + (l>>3);
    m0 = (wid % nx)*BM; n0 = (wid / nx)*BN;
  } else {
    m0 = blockIdx.x*BM; n0 = blockIdx.y*BN;
  }
  const int z = blockIdx.z;
  const int tid = threadIdx.x, lane = tid&63, w = tid>>6;
  const int wr = w/WN, wc = w%WN;
  const int rsub = lane/LPR;
  const int col8 = (((lane%LPR) ^ (rsub&(LPR-1))))*8;
  const int kq = lane>>4;
  const u16* Ahi = Ahip + (long)z*zA + (GATH==4 ? (long)eid_*T_*lda : 0);
  const u16* Alo = SPL ? (Alop + (long)z*zA + (GATH==4 ? (long)eid_*T_*lda : 0)) : (const u16*)nullptr;
  const u16* Bh  = Bhip + (long)(z/zBdiv)*zB + (GATH==4 ? (long)eid_*zB : 0);
  const u16* Bl  = SPL ? (Blop + (long)(z/zBdiv)*zB + (GATH==4 ? (long)eid_*zB : 0)) : (const u16*)nullptr;

  f32x4 acc[MF][NF];
  #pragma unroll
  for(int i=0;i<MF;i++)
    #pragma unroll
    for(int j=0;j<NF;j++){ f32x4 zv={0.f,0.f,0.f,0.f}; acc[i][j]=zv; }

  const int ktend = Kdim/BKT;

  auto stage = [&](int kt, int bo){
    u16* As = (u16*)(smem + bo);
    u16* Bs = (u16*)(smem + bo + ABY);
    const int k0 = kt*BKT;
    #pragma unroll
    for(int s=0;s<ACn;s++){
      int ch = s*Wv + w;
      int arow = m0 + ch*LR + rsub;
      if constexpr (GATH==4){ arow = arow < cnt ? arow : cnt-1; }
      gl16(Ahi + (long)arow*lda + k0+col8, &As[ch*512]);
      if constexpr (SPL) gl16(Alo + (long)arow*lda + k0+col8, &As[BM*BKT + ch*512]);
    }
    #pragma unroll
    for(int s=0;s<BCn;s++){
      int ch = s*Wv + w;
      int brow = n0 + ch*LR + rsub;
      gl16(Bh + (long)brow*ldb + k0+col8, &Bs[ch*512]);
      if constexpr (SPL) gl16(Bl + (long)brow*ldb + k0+col8, &Bs[BN*BKT + ch*512]);
    }
  };

  auto compute = [&](int bo){
    u16* As = (u16*)(smem + bo);
    u16* Bs = (u16*)(smem + bo + ABY);
    #pragma unroll
    for(int ks=0;ks<KS;ks++){
      s16x8 ah[MF], al[MF], bh[NF], bl[NF];
      #pragma unroll
      for(int i=0;i<MF;i++){
        int row = wr*WMT+i*16+(lane&15);
        int sl = ((ks*4+kq) ^ (row&(LPR-1)))*8;
        ah[i]=*(const s16x8*)&As[row*BKT+sl];
        if constexpr (SPL) al[i]=*(const s16x8*)&As[BM*BKT+row*BKT+sl];
      }
      #pragma unroll
      for(int j=0;j<NF;j++){
        int row = wc*WNT+j*16+(lane&15);
        int sl = ((ks*4+kq) ^ (row&(LPR-1)))*8;
        bh[j]=*(const s16x8*)&Bs[row*BKT+sl];
        if constexpr (SPL) bl[j]=*(const s16x8*)&Bs[BN*BKT+row*BKT+sl];
      }
      #pragma unroll
      for(int i=0;i<MF;i++)
        #pragma unroll
        for(int j=0;j<NF;j++){
          acc[i][j]=__builtin_amdgcn_mfma_f32_16x16x32_bf16(ah[i],bh[j],acc[i][j],0,0,0);
          if constexpr (SPL){
            acc[i][j]=__builtin_amdgcn_mfma_f32_16x16x32_bf16(ah[i],bl[j],acc[i][j],0,0,0);
            acc[i][j]=__builtin_amdgcn_mfma_f32_16x16x32_bf16(al[i],bh[j],acc[i][j],0,0,0);
          }
        }
    }
  };

  if constexpr (PIPE){
    stage(0, 0);
    __syncthreads();
    for(int kt=0;kt<ktend;kt++){
      int cur = kt&1;
      if(kt+1<ktend) stage(kt+1, (cur^1)*STEP);
      compute(cur*STEP);
      __syncthreads();
    }
  } else {
    for(int kt=0;kt<ktend;kt++){
      __syncthreads();
      stage(kt, 0);
      __syncthreads();
      compute(0);
    }
  }

  if constexpr (EPI==8){
    float* C = (float*)Cp + (long)z*zC;
    #pragma unroll
    for(int i=0;i<MF;i++){
      __syncthreads();
      #pragma unroll
      for(int j=0;j<NF;j++)
        #pragma unroll
        for(int r=0;r<4;r++)
          Csf[wr*16*(BN+4) + (((lane>>4)<<2)+r)*(BN+4) + wc*WNT + j*16 + (lane&15)] = acc[i][j][r]*scale;
      __syncthreads();
      const int rrow = tid>>3;
      const int wri = rrow>>4, r16 = rrow&15;
      const long gm = m0 + wri*WMT + i*16 + r16;
      #pragma unroll
      for(int s=0;s<BN/32;s++){
        int c0 = ((tid&7) + s*8)*4;
        const float* Cr = &Csf[wri*16*(BN+4) + r16*(BN+4)];
        float4 vv = { Cr[c0], Cr[c0+1], Cr[c0+2], Cr[c0+3] };
        *(float4*)(C + gm*ldc + n0 + c0) = vv;
      }
    }
    return;
  }

  #pragma unroll
  for(int i=0;i<MF;i++){
    #pragma unroll
    for(int j=0;j<NF;j++){
      const int gm0 = m0 + wr*WMT + i*16 + ((lane>>4)<<2);
      const int gn  = n0 + wc*WNT + j*16 + (lane&15);
      #pragma unroll
      for(int r=0;r<4;r++){
        const int gm = gm0+r;
        const float v = acc[i][j][r];
        const bool live = (GATH==0) || (gm < cnt);
        if constexpr (EPI==1){
          if(live) ((float*)Cp + (long)z*zC)[(long)gm*ldc+gn] = v*scale;
        } else if constexpr (EPI==2){
          float* C = (float*)Cp; C[(long)gm*ldc+gn] += v;
        } else if constexpr (EPI==7){
          if(live) ((float*)Cp)[(long)(eid_*T_+gm)*ldc+gn] = v*scale;
        } else if constexpr (EPI==9){
          u16* Ch = (u16*)Cp + (long)z*zC;
          u16* Cl = (u16*)auxp + (long)z*zC;
          long idx = (long)gm*ldc+gn;
          u16 hv = f2b(v);
          Ch[idx]=hv; Cl[idx]=f2b(v-b2f(hv));
        }
      }
    }
  }
}

extern "C" void kernel_launch(void* const* d_in, const int* in_sizes, int n_in,
                              void* d_out, int out_size, void* d_ws, size_t ws_size,
                              hipStream_t stream)
{
  (void)in_sizes; (void)n_in; (void)out_size;
  const int*   ids   = (const int*)d_in[0];
  const float* emb   = (const float*)d_in[1];
  const float* Wq    = (const float*)d_in[2];
  const float* Wk    = (const float*)d_in[3];
  const float* Wv    = (const float*)d_in[4];
  const float* Wo    = (const float*)d_in[5];
  const float* ln1   = (const float*)d_in[6];
  const float* ln2   = (const float*)d_in[7];
  const float* gate  = (const float*)d_in[8];
  const float* Wg    = (const float*)d_in[9];
  const float* Wu    = (const float*)d_in[10];
  const float* Wd    = (const float*)d_in[11];
  const float* normw = (const float*)d_in[12];
  const float* lmh   = (const float*)d_in[13];

  char* p = (char*)d_ws;
  auto carve = [&](size_t bytes)->void*{ void* r=p; p += (bytes+255)&~(size_t)255; return r; };
  float* h    = (float*)carve((size_t)T_*H_*4);
  u16*   xhi  = (u16*)  carve((size_t)T_*H_*2);
  u16*   xlo  = (u16*)  carve((size_t)T_*H_*2);
  u16*   qhi  = (u16*)  carve((size_t)T_*NHD*2);
  u16*   qlo  = (u16*)  carve((size_t)T_*NHD*2);
  u16*   khi  = (u16*)  carve((size_t)T_*KVD*2);
  u16*   klo  = (u16*)  carve((size_t)T_*KVD*2);
  u16*   vthi = (u16*)  carve((size_t)T_*KVD*2);
  u16*   vtlo = (u16*)  carve((size_t)T_*KVD*2);
  u16*   ohi  = (u16*)  carve((size_t)T_*NHD*2);
  u16*   olo  = (u16*)  carve((size_t)T_*NHD*2);
  float* comb = (float*)carve((size_t)T_*4*4);
  int*   cnt  = (int*)  carve((size_t)16*4);
  int*   lists= (int*)  carve((size_t)4*T_*4);
  int2*  epos = (int2*) carve((size_t)T_*8);
  char*  U    = (char*) carve((size_t)112*1024*1024);
  u16*   wp   = (u16*)  carve((size_t)56623104*2);
  if ((size_t)(p - (char*)d_ws) > ws_size) return;

  u16*   guh  = (u16*)U;
  u16*   gul  = (u16*)(U + 33554432);
  float* eo   = (float*)(U + 67108864);

  u16 *WqkvTh = wp,          *WqkvTl = wp+2097152;
  u16 *WoTh = wp+4194304,    *WoTl = wp+5242880;
  u16 *WgTh = wp+6291456,    *WgTl = wp+14680064;
  u16 *WuTh = wp+23068672,   *WuTl = wp+31457280;
  u16 *WdTh = wp+39845888,   *WdTl = wp+48234496;

  dim3 tb(32,8);

  k_embed<<<T_,256,0,stream>>>(ids, emb, h, cnt);

  for(int l=0;l<4;l++){
    k_wtrans<<<27648,tb,0,stream>>>(
      Wq+(size_t)l*H_*NHD, Wk+(size_t)l*H_*KVD, Wv+(size_t)l*H_*KVD, Wo+(size_t)l*NHD*H_,
      Wg+(size_t)l*4*H_*I_, Wu+(size_t)l*4*H_*I_, Wd+(size_t)l*4*I_*H_,
      WqkvTh, WqkvTl, WoTh, WoTl, WgTh, WgTl, WuTh, WuTl, WdTh, WdTl);

    if(l==0) k_rms_sp<<<T_/4,256,0,stream>>>(h, ln1, xhi, xlo);

    k_qkv<<<dim3(16,16),256,0,stream>>>(xhi, xlo, WqkvTh, WqkvTl, qhi, qlo, khi, klo, vthi, vtlo);

    k_flash<<<dim3(8,16,2),512,0,stream>>>(qhi, qlo, khi, klo, vthi, vtlo, ohi, olo);

    k_gemm<64,128,2,2,64,true,2,0,false,false><<<dim3(32,8,1),256,0,stream>>>(
      ohi, olo, WoTh, WoTl, h, nullptr, nullptr, NHD, NHD, NHD, H_, 0,0,1,0, 0.f);

    k_router<<<T_/4,256,0,stream>>>(h, ln2+(size_t)l*H_, gate+(size_t)l*H_*4, comb, lists, cnt+l*4, epos, xhi, xlo);

    k_moe_ug<<<2048,256,0,stream>>>(xhi, xlo, WuTh, WuTl, WgTh, WgTl, guh, gul, lists, cnt+l*4);
    k_gemm<128,128,2,2,64,true,7,4,false,false><<<512,256,0,stream>>>(
      guh, gul, WdTh, WdTl, eo, nullptr, cnt+l*4, I_, I_, I_, H_, 0, (long)I_*H_, 1, 0, 1.f);
    if(l<3)
      k_combine<<<T_,256,0,stream>>>(h, eo, epos, comb, ln1+(size_t)(l+1)*H_, xhi, xlo);
    else
      k_combine<<<T_,256,0,stream>>>(h, eo, epos, comb, normw, xhi, nullptr);
  }

  k_transpose<<<dim3(1000,32),tb,0,stream>>>(lmh, wp, nullptr, H_, V_, 0,0);
  // lm_head: 256^2 tile, counted-vmcnt 2-barrier schedule
  k_lmhead<<<1000,512,0,stream>>>(xhi, wp, (float*)d_out);
}